// Round 10
// baseline (1136.136 us; speedup 1.0000x reference)
//
#include <hip/hip_runtime.h>
#include <cstdint>
#include <cstddef>

#define NN 80000
#define NE 500000
#define NG 2000
#define DD 256
#define RR 4
#define LL 3
#define UNITS_TH 150
#define NRSEG (NN*RR)
#define SSEG (3*NRSEG)        // 960000 segments across 3 conv types
#define RD (RR*DD)            // 1024
#define KTOT (RD+DD)          // 1280 (row stride 2560B, non-pow2)
#define ROWS_CM 46080         // mono-region rows (mean 44776, sigma~140)
#define ROWS_AT 36352         // atom-region rows (mean 35224, sigma~140)

// MFMA GEMM tile (proven best: 128x128, 256 thr, 66KB LDS, 2 blocks/CU)
#define GBM 128
#define GBN 128
#define GXT ((NN + GBM - 1) / GBM)       // 625 row-tiles
#define GNBLK (16 * ((GXT + 7) / 8))     // pair-swizzled 1-D grid

typedef __attribute__((ext_vector_type(8))) short bf16x8;
typedef __attribute__((ext_vector_type(4))) float f32x4;

__device__ __forceinline__ ushort f2bf(float f) {
    union { float f; uint32_t u; } c; c.f = f;
    uint32_t u = c.u;
    return (ushort)((u + 0x7FFFu + ((u >> 16) & 1u)) >> 16);
}
__device__ __forceinline__ float bf2f(ushort h) {
    union { uint32_t u; float f; } c; c.u = ((uint32_t)h) << 16;
    return c.f;
}

__device__ __forceinline__ void gload16(const void* g, void* l) {
    __builtin_amdgcn_global_load_lds(
        (const __attribute__((address_space(1))) unsigned int*)g,
        (__attribute__((address_space(3))) unsigned int*)l, 16, 0, 0);
}

__device__ inline int edge_type(const int* ut, int s, int d) {
    bool ain = ut[s] >= UNITS_TH, aout = ut[d] >= UNITS_TH;
    return ain ? (aout ? 0 : 1) : (aout ? 3 : 2);  // 3 = unused (m->a)
}

// xbf[n,:] = bf16(emb[ut[n],:])  (or 0)
__global__ void k_init_xbf(const int* __restrict__ ut, const float* __restrict__ emb,
                           ushort* __restrict__ x)
{
    int tid = blockIdx.x * blockDim.x + threadIdx.x;
    int n = tid >> 6, lane = tid & 63;
    if (n >= NN) return;
    int t = ut[n];
    ushort4 u = make_ushort4(0, 0, 0, 0);
    if (t >= 0) {
        float4 v = *reinterpret_cast<const float4*>(emb + (size_t)t * DD + lane * 4);
        u.x = f2bf(v.x); u.y = f2bf(v.y); u.z = f2bf(v.z); u.w = f2bf(v.w);
    }
    *reinterpret_cast<ushort4*>(x + (size_t)n * DD + lane * 4) = u;
}

// wave-aggregated list build: one atomic per wave per class
__global__ void k_lists(const int* __restrict__ ut, int* __restrict__ atom_list,
                        int* __restrict__ mono_list, int* __restrict__ cnt)
{
    int n = blockIdx.x * blockDim.x + threadIdx.x;
    bool valid = n < NN;
    bool atom = valid && (ut[n] >= UNITS_TH);
    bool mono = valid && (ut[n] < UNITS_TH);
    unsigned long long ma = __ballot(atom);
    unsigned long long mb = __ballot(mono);
    int lane = threadIdx.x & 63;
    unsigned long long below = (1ull << lane) - 1ull;
    int ra = __popcll(ma & below);
    int rm = __popcll(mb & below);
    int basea = 0, basem = 0;
    if (lane == 0) {
        if (ma) basea = atomicAdd(cnt + 0, __popcll(ma));
        if (mb) basem = atomicAdd(cnt + 1, __popcll(mb));
    }
    basea = __shfl(basea, 0);
    basem = __shfl(basem, 0);
    if (atom) atom_list[basea + ra] = n;
    if (mono) mono_list[basem + rm] = n;
}

// weights: Wcat[n][0:1024]=W[n][:], [1024:1280]=Ws[n][:], bf16; bias2 = b+bs
__global__ void k_wcat(const float* __restrict__ W, const float* __restrict__ Ws,
                       const float* __restrict__ b, const float* __restrict__ bs,
                       ushort* __restrict__ out, float* __restrict__ bias2)
{
    int n = blockIdx.x;
    const float* wr = W + (size_t)n * RD;
    const float* wsr = Ws + (size_t)n * DD;
    ushort* o = out + (size_t)n * KTOT;
    for (int k = threadIdx.x; k < RD; k += 256) o[k] = f2bf(wr[k]);
    for (int k = threadIdx.x; k < DD; k += 256) o[RD + k] = f2bf(wsr[k]);
    if (threadIdx.x == 0) bias2[n] = b[n] + bs[n];
}

// ---- CSR build (layer-invariant, built once) ----
__global__ void k_csr_count(const int* __restrict__ ut, const int* __restrict__ esrc,
                            const int* __restrict__ edst, const int* __restrict__ erel,
                            int* __restrict__ cnt3)
{
    int e = blockIdx.x * blockDim.x + threadIdx.x;
    if (e >= NE) return;
    int s = esrc[e], d = edst[e];
    int t = edge_type(ut, s, d);
    if (t == 3) return;
    atomicAdd(&cnt3[t * NRSEG + d * RR + erel[e]], 1);
}

__global__ void k_scan_a(const int* __restrict__ in, int* __restrict__ out,
                         int* __restrict__ bsum, int S)
{
    __shared__ int sh[256];
    int base = blockIdx.x * 1024 + threadIdx.x * 4;
    int v[4];
    #pragma unroll
    for (int j = 0; j < 4; j++) v[j] = (base + j < S) ? in[base + j] : 0;
    int tsum = v[0] + v[1] + v[2] + v[3];
    sh[threadIdx.x] = tsum;
    __syncthreads();
    for (int ofs = 1; ofs < 256; ofs <<= 1) {
        int a = sh[threadIdx.x];
        int b = (threadIdx.x >= ofs) ? sh[threadIdx.x - ofs] : 0;
        __syncthreads();
        sh[threadIdx.x] = a + b;
        __syncthreads();
    }
    int excl = sh[threadIdx.x] - tsum;
    if (threadIdx.x == 255) bsum[blockIdx.x] = sh[255];
    int run = excl;
    #pragma unroll
    for (int j = 0; j < 4; j++) {
        if (base + j < S) out[base + j] = run;
        run += v[j];
    }
}

__global__ void k_scan_b(int* __restrict__ bsum, int* __restrict__ total, int NB)
{
    __shared__ int sh[1024];
    int t = threadIdx.x;
    int o = (t < NB) ? bsum[t] : 0;
    sh[t] = o;
    __syncthreads();
    for (int ofs = 1; ofs < 1024; ofs <<= 1) {
        int a = sh[t];
        int b = (t >= ofs) ? sh[t - ofs] : 0;
        __syncthreads();
        sh[t] = a + b;
        __syncthreads();
    }
    if (t < NB) bsum[t] = sh[t] - o;
    if (t == 0) *total = sh[1023];
}

__global__ void k_scan_c(int* __restrict__ rowptr, const int* __restrict__ bofs,
                         const int* __restrict__ total, int S)
{
    int add = bofs[blockIdx.x];
    int base = blockIdx.x * 1024 + threadIdx.x * 4;
    #pragma unroll
    for (int j = 0; j < 4; j++)
        if (base + j < S) rowptr[base + j] += add;
    if (blockIdx.x == 0 && threadIdx.x == 0) rowptr[S] = *total;
}

__global__ void k_csr_fill(const int* __restrict__ ut, const int* __restrict__ esrc,
                           const int* __restrict__ edst, const int* __restrict__ erel,
                           const float* __restrict__ ew, const int* __restrict__ rowptr,
                           int* __restrict__ fill, int* __restrict__ csrc,
                           float* __restrict__ cw)
{
    int e = blockIdx.x * blockDim.x + threadIdx.x;
    if (e >= NE) return;
    int s = esrc[e], d = edst[e];
    int t = edge_type(ut, s, d);
    if (t == 3) return;
    int seg = t * NRSEG + d * RR + erel[e];
    int pos = atomicAdd(&fill[seg], 1);
    int slot = rowptr[seg] + pos;
    csrc[slot] = s;
    cw[slot] = ew[e];
}

// normalize weights in place: cw[e] = (cw[e]>0) ? cw[e]/deg : 0, deg = sum over segment
__global__ void k_norm(const int* __restrict__ rowptr, float* __restrict__ cw)
{
    int s = blockIdx.x * blockDim.x + threadIdx.x;
    if (s >= SSEG) return;
    int a = rowptr[s], b = rowptr[s + 1];
    if (a == b) return;
    float deg = 0.f;
    for (int e = a; e < b; ++e) deg += cw[e];
    float inv = 1.f / ((deg > 0.f) ? deg : 1.f);
    for (int e = a; e < b; ++e) {
        float w = cw[e];
        cw[e] = (w > 0.f) ? w * inv : 0.f;
    }
}

// shared gather body: one wave computes compacted row i (4 rels + self copy)
__device__ __forceinline__ void gather_node(
    const ushort* __restrict__ xsrc, const ushort* __restrict__ xselfp,
    const int* __restrict__ rowptr, const int* __restrict__ csrc,
    const float* __restrict__ cw, ushort* __restrict__ updc,
    const int* __restrict__ list, int i, int t, int lane)
{
    int node = list[i];
    ushort* orow = updc + (size_t)i * KTOT;
    int segbase = t * NRSEG + node * RR;
    #pragma unroll
    for (int rel = 0; rel < RR; ++rel) {
        int s0 = rowptr[segbase + rel];
        int s1 = rowptr[segbase + rel + 1];
        float a0 = 0.f, a1 = 0.f, a2 = 0.f, a3 = 0.f;
        for (int e = s0; e < s1; ++e) {
            float f = cw[e];   // pre-normalized; zero edges contribute exactly 0
            int src = csrc[e];
            ushort4 v = *reinterpret_cast<const ushort4*>(xsrc + (size_t)src * DD + lane * 4);
            a0 += f * bf2f(v.x); a1 += f * bf2f(v.y);
            a2 += f * bf2f(v.z); a3 += f * bf2f(v.w);
        }
        ushort4 u;
        u.x = f2bf(a0); u.y = f2bf(a1); u.z = f2bf(a2); u.w = f2bf(a3);
        *reinterpret_cast<ushort4*>(orow + rel * DD + lane * 4) = u;
    }
    // self-term copy (bit-identical to reading xselfp in the GEMM)
    ushort4 sv = *reinterpret_cast<const ushort4*>(xselfp + (size_t)node * DD + lane * 4);
    *reinterpret_cast<ushort4*>(orow + RD + lane * 4) = sv;
}

// ---- standalone gather (wave-per-node) ----
__global__ void k_gather(const ushort* __restrict__ xsrc, const ushort* __restrict__ xselfp,
                         const int* __restrict__ rowptr,
                         const int* __restrict__ csrc, const float* __restrict__ cw,
                         ushort* __restrict__ updc, const int* __restrict__ list,
                         const int* __restrict__ cnt, int cnt_idx, int t)
{
    int i = blockIdx.x * 4 + (threadIdx.x >> 6);
    if (i >= cnt[cnt_idx]) return;
    gather_node(xsrc, xselfp, rowptr, csrc, cw, updc, list, i, t, threadIdx.x & 63);
}

// ---- MFMA conv GEMM (proven structure: sequential A, XCD pair-swizzle) +
// optional appended gather phase (next layer's atom gather; barrier-free,
// runs after all conv barriers; early-exit blocks go straight to gathering) ----
template<int CTYPE>
__global__ __launch_bounds__(256) void k_conv(
    const ushort* __restrict__ updc, const ushort* __restrict__ Wc,
    const float* __restrict__ bias2,
    ushort* __restrict__ obf, float* __restrict__ of32,
    float* __restrict__ nf32, int wf32, int nzero,
    const int* __restrict__ list, const int* __restrict__ cnt, int cnt_idx,
    // fused gather (type0, atom) for next layer; gdo=0 disables
    const ushort* __restrict__ gx, const int* __restrict__ growptr,
    const int* __restrict__ gcsrc, const float* __restrict__ gcw,
    ushort* __restrict__ gupd, const int* __restrict__ glist, int gcnt_idx, int gdo)
{
    // LDS pool: [0,32K) As dbuf, [32K,64K) Bs dbuf, [64K,64.5K) rowsS.
    // Epilogue aliases [0,64K) as f32 out-tile [128][128].
    __shared__ __align__(16) char smem[66048];
    int* rowsS = (int*)(smem + 65536);

    int count = cnt[cnt_idx];
    int id = blockIdx.x;
    int g = id >> 4, o = id & 15;
    int y = (o >> 3) & 1;
    int x = (g << 3) | (o & 7);
    int bm = x * GBM;
    int n0 = y * GBN;
    int tid = threadIdx.x;
    int wid = tid >> 6, lane = tid & 63;

    if (bm < count) {
        if (tid < GBM) {
            int r = bm + tid;
            rowsS[tid] = (r < count) ? list[r] : 0;   // tail rows masked at write
        }
        __syncthreads();   // rowsS visible; vmcnt drained -> pipeline count clean

        int srow = lane >> 3;                  // row within 8-row group
        int schunk = (lane & 7) ^ srow;        // swizzled 16B chunk to fetch

        const ushort* baseA[4];
        const ushort* baseW[4];
        #pragma unroll
        for (int it = 0; it < 4; ++it) {
            int m = bm + it * 32 + wid * 8 + srow;               // sequential rows
            baseA[it] = updc + (size_t)m * KTOT + schunk * 8;
            int n = n0 + it * 32 + wid * 8 + srow;
            baseW[it] = Wc + (size_t)n * KTOT + schunk * 8;
        }

        int lr = lane & 15;
        int cbase = (lane >> 4) << 4;   // byte col offset of this lane's 16B frag

        f32x4 acc[4][4] = {};

        auto stage = [&](int t, int buf) {
            int k0 = t * 64;
            char* Ad = smem + buf * 16384 + wid * 1024;
            char* Bd = smem + 32768 + buf * 16384 + wid * 1024;
            #pragma unroll
            for (int it = 0; it < 4; ++it)
                gload16(baseA[it] + k0, Ad + it * 4096);
            #pragma unroll
            for (int it = 0; it < 4; ++it)
                gload16(baseW[it] + k0, Bd + it * 4096);
        };

        auto compute = [&](int buf) {
            const char* Ab = smem + buf * 16384;
            const char* Bb = smem + 32768 + buf * 16384;
            __builtin_amdgcn_s_setprio(1);
            #pragma unroll
            for (int ks = 0; ks < 2; ++ks) {
                int cb = ks * 64 + cbase;
                int cslot = cb >> 4;
                bf16x8 af[4], bfr[4];
                #pragma unroll
                for (int i = 0; i < 4; i++) {
                    int row = (wid & 1) * 64 + i * 16 + lr;
                    af[i] = *reinterpret_cast<const bf16x8*>(
                        Ab + row * 128 + ((cslot ^ (row & 7)) << 4));
                }
                #pragma unroll
                for (int j = 0; j < 4; j++) {
                    int row = (wid >> 1) * 64 + j * 16 + lr;
                    bfr[j] = *reinterpret_cast<const bf16x8*>(
                        Bb + row * 128 + ((cslot ^ (row & 7)) << 4));
                }
                #pragma unroll
                for (int i = 0; i < 4; i++)
                    #pragma unroll
                    for (int j = 0; j < 4; j++)
                        acc[i][j] = __builtin_amdgcn_mfma_f32_16x16x32_bf16(af[i], bfr[j], acc[i][j], 0, 0, 0);
            }
            __builtin_amdgcn_s_setprio(0);
        };

        const int NT = KTOT / 64;   // 20

        stage(0, 0);
        __builtin_amdgcn_sched_barrier(0);
        stage(1, 1);
        __builtin_amdgcn_sched_barrier(0);

        for (int t = 0; t < NT; ++t) {
            int cur = t & 1;
            if (t < NT - 1) asm volatile("s_waitcnt vmcnt(8)" ::: "memory");
            else            asm volatile("s_waitcnt vmcnt(0)" ::: "memory");
            __builtin_amdgcn_s_barrier();
            compute(cur);
            asm volatile("" ::: "memory");
            __builtin_amdgcn_s_barrier();
            if (t + 2 < NT) stage(t + 2, cur);
        }

        // ---- epilogue: bias+relu -> LDS f32 tile -> full-line global stores ----
        float* ftile = (float*)smem;
        int wm = (wid & 1) * 64;
        int wn = (wid >> 1) * 64;
        float bcol[4];
        #pragma unroll
        for (int j = 0; j < 4; j++) bcol[j] = bias2[n0 + wn + j * 16 + lr];
        #pragma unroll
        for (int i = 0; i < 4; i++) {
            int r0 = wm + i * 16 + (lane >> 4) * 4;
            #pragma unroll
            for (int j = 0; j < 4; j++) {
                int c = wn + j * 16 + lr;
                #pragma unroll
                for (int q = 0; q < 4; q++) {
                    float v = acc[i][j][q] + bcol[j];
                    ftile[(r0 + q) * 128 + c] = fmaxf(v, 0.f);
                }
            }
        }
        __syncthreads();
        int rbase = wid * 32;
        int cc = (lane & 31) * 4;
        #pragma unroll
        for (int p = 0; p < 16; ++p) {
            int row = rbase + p * 2 + (lane >> 5);
            f32x4 v = *reinterpret_cast<const f32x4*>(ftile + row * 128 + cc);
            if (bm + row < count) {
                int node = rowsS[row];
                int c = n0 + cc;
                if (obf) {
                    ushort4 ub;
                    ub.x = f2bf(v[0]); ub.y = f2bf(v[1]); ub.z = f2bf(v[2]); ub.w = f2bf(v[3]);
                    *reinterpret_cast<ushort4*>(obf + (size_t)node * DD + c) = ub;
                }
                if (wf32) {
                    float4 fv = make_float4(v[0], v[1], v[2], v[3]);
                    *reinterpret_cast<float4*>(of32 + (size_t)node * DD + c) = fv;
                    float4 nv = nzero ? make_float4(0.f, 0.f, 0.f, 0.f) : fv;
                    *reinterpret_cast<float4*>(nf32 + (size_t)node * DD + c) = nv;
                }
            }
        }
    }

    // ---- fused gather phase (next layer's atom gather, type0) ----
    if (gdo) {
        int gcount = cnt[gcnt_idx];
        int gw = id * 4 + wid;
        int nw = (int)gridDim.x * 4;
        for (int i = gw; i < gcount; i += nw)
            gather_node(gx, gx, growptr, gcsrc, gcw, gupd, glist, i, 0, lane);
    }
}

__global__ void k_gbounds(const int* __restrict__ n2g, int* __restrict__ gs,
                          int* __restrict__ ge)
{
    int n = blockIdx.x * blockDim.x + threadIdx.x;
    if (n >= NN) return;
    int g = n2g[n];
    atomicMin(&gs[g], n);
    atomicMax(&ge[g], n + 1);
}

__global__ void k_graph(const int* __restrict__ ut, const int* __restrict__ n2g,
                        const float* __restrict__ aout, const int* __restrict__ gs,
                        const int* __restrict__ ge, float* __restrict__ gout)
{
    int g = blockIdx.x * 4 + (threadIdx.x >> 6);
    if (g >= NG) return;
    int lane = threadIdx.x & 63;
    float a0 = 0.f, a1 = 0.f, a2 = 0.f, a3 = 0.f;
    int s = gs[g], e = ge[g];
    if (s < e) {
        for (int n = s; n < e; ++n) {
            if (n2g[n] != g || ut[n] >= UNITS_TH) continue;
            float4 v = *reinterpret_cast<const float4*>(aout + (size_t)n * DD + lane * 4);
            a0 += v.x; a1 += v.y; a2 += v.z; a3 += v.w;
        }
    }
    *reinterpret_cast<float4*>(gout + (size_t)g * DD + lane * 4) =
        make_float4(a0, a1, a2, a3);
}

extern "C" void kernel_launch(void* const* d_in, const int* in_sizes, int n_in,
                              void* d_out, int out_size, void* d_ws, size_t ws_size,
                              hipStream_t stream)
{
    (void)in_sizes; (void)n_in;
    const int* ut    = (const int*)d_in[0];
    const int* esrc  = (const int*)d_in[1];
    const int* edst  = (const int*)d_in[2];
    const int* erel  = (const int*)d_in[3];
    const float* ew  = (const float*)d_in[4];
    const int* n2g   = (const int*)d_in[5];
    const float* emb = (const float*)d_in[6];
    const float* Wp[3]  = {(const float*)d_in[7],  (const float*)d_in[11], (const float*)d_in[15]};
    const float* bp[3]  = {(const float*)d_in[8],  (const float*)d_in[12], (const float*)d_in[16]};
    const float* Wsp[3] = {(const float*)d_in[9],  (const float*)d_in[13], (const float*)d_in[17]};
    const float* bsp[3] = {(const float*)d_in[10], (const float*)d_in[14], (const float*)d_in[18]};

    float* outp = (float*)d_out;
    float* gout = outp;                                  // [G, D]
    float* nout = outp + (size_t)NG * DD;                // [N, D]
    float* aout = nout + (size_t)NN * DD;                // [N, D] final f32 features

    char* wsb = (char*)d_ws;
    size_t off = 0;
    auto alloc = [&](size_t bytes) -> void* {
        void* p = wsb + off;
        off += (bytes + 255) & ~(size_t)255;
        return p;
    };
    ushort* xA     = (ushort*)alloc((size_t)(NN + 1) * DD * 2);    // 41 MB
    ushort* xB     = (ushort*)alloc((size_t)(NN + 1) * DD * 2);    // 41 MB
    ushort* h2bf   = (ushort*)alloc((size_t)(NN + 1) * DD * 2);    // 41 MB
    ushort* updcA  = (ushort*)alloc((size_t)ROWS_CM * KTOT * 2);   // 118 MB (cross/mono)
    ushort* updcB  = (ushort*)alloc((size_t)ROWS_AT * KTOT * 2);   // 93 MB (atom chain)
    ushort* Wcat   = (ushort*)alloc((size_t)9 * DD * KTOT * 2);    // 5.9 MB
    float* bias2   = (float*)alloc((size_t)9 * DD * 4);
    int* csrc      = (int*)alloc((size_t)NE * 4);
    float* cw      = (float*)alloc((size_t)NE * 4);
    int* rowptr    = (int*)alloc((size_t)(SSEG + 1) * 4);
    int* cnt3      = (int*)alloc((size_t)SSEG * 4);
    int* bsum      = (int*)alloc(1024 * 4);
    int* total     = (int*)alloc(256);
    int* atom_list = (int*)alloc((size_t)NN * 4);
    int* mono_list = (int*)alloc((size_t)NN * 4);
    int* cnt       = (int*)alloc(256);
    int* gs        = (int*)alloc((size_t)NG * 4);
    int* ge        = (int*)alloc((size_t)NG * 4);

    if (off > ws_size) {
        hipMemsetAsync(d_out, 0x7F, (size_t)out_size * 4, stream);
        return;
    }

    const int NB = (SSEG + 1023) / 1024;

    // ---- one-time precompute ----
    hipMemsetAsync(cnt, 0, 8, stream);
    hipMemsetAsync(cnt3, 0, (size_t)SSEG * 4, stream);
    hipMemsetAsync(gs, 0x7F, (size_t)NG * 4, stream);
    hipMemsetAsync(ge, 0, (size_t)NG * 4, stream);

    k_init_xbf<<<dim3((NN * 64 + 255) / 256), 256, 0, stream>>>(ut, emb, xA);
    k_lists<<<dim3((NN + 255) / 256), 256, 0, stream>>>(ut, atom_list, mono_list, cnt);
    for (int t = 0; t < 3; ++t) {
        for (int l = 0; l < 3; ++l) {
            int tl = t * 3 + l;
            k_wcat<<<dim3(DD), 256, 0, stream>>>(
                Wp[t] + (size_t)l * DD * RD, Wsp[t] + (size_t)l * DD * DD,
                bp[t] + (size_t)l * DD, bsp[t] + (size_t)l * DD,
                Wcat + (size_t)tl * DD * KTOT, bias2 + (size_t)tl * DD);
        }
    }
    k_csr_count<<<dim3((NE + 255) / 256), 256, 0, stream>>>(ut, esrc, edst, erel, cnt3);
    k_scan_a<<<dim3(NB), 256, 0, stream>>>(cnt3, rowptr, bsum, SSEG);
    k_scan_b<<<dim3(1), 1024, 0, stream>>>(bsum, total, NB);
    k_scan_c<<<dim3(NB), 256, 0, stream>>>(rowptr, bsum, total, SSEG);
    hipMemsetAsync(cnt3, 0, (size_t)SSEG * 4, stream);
    k_csr_fill<<<dim3((NE + 255) / 256), 256, 0, stream>>>(ut, esrc, edst, erel, ew,
                                                           rowptr, cnt3, csrc, cw);
    k_norm<<<dim3((SSEG + 255) / 256), 256, 0, stream>>>(rowptr, cw);
    k_gbounds<<<dim3((NN + 255) / 256), 256, 0, stream>>>(n2g, gs, ge);

    dim3 ggrid(GNBLK);
    int ngrid = (NN + 3) / 4;

    ushort* xprev = xA;
    ushort* xcur  = xB;

    // layer-0 atom gather (standalone, atom region)
    k_gather<<<ngrid, 256, 0, stream>>>(xprev, xprev, rowptr, csrc, cw, updcB,
                                        atom_list, cnt, 0, 0);

    for (int l = 0; l < LL; ++l) {
        int last = (l == LL - 1) ? 1 : 0;
        const ushort* Wa = Wcat + (size_t)(0 * 3 + l) * DD * KTOT;
        const ushort* Wc_ = Wcat + (size_t)(1 * 3 + l) * DD * KTOT;
        const ushort* Wm = Wcat + (size_t)(2 * 3 + l) * DD * KTOT;
        const float* ba = bias2 + (size_t)(0 * 3 + l) * DD;
        const float* bc = bias2 + (size_t)(1 * 3 + l) * DD;
        const float* bm_ = bias2 + (size_t)(2 * 3 + l) * DD;

        // conv_atom: A = updcB (gathered by standalone ga0 or prior fused phase)
        k_conv<0><<<ggrid, 256, 0, stream>>>(updcB, Wa, ba, xcur, aout, nout,
                                             last, 1, atom_list, cnt, 0,
                                             nullptr, nullptr, nullptr, nullptr,
                                             nullptr, nullptr, 0, 0);

        // conv_cross gather (type1, src atom -> xcur); self xprev (mono rows)
        k_gather<<<ngrid, 256, 0, stream>>>(xcur, xprev, rowptr, csrc, cw, updcA,
                                            mono_list, cnt, 1, 1);
        // conv_cross + FUSED next-layer atom gather (sources = xcur atom rows,
        // written by conv_atom above; independent of this conv's work)
        k_conv<1><<<ggrid, 256, 0, stream>>>(updcA, Wc_, bc, h2bf, nullptr, nullptr,
                                             0, 0, mono_list, cnt, 1,
                                             xcur, rowptr, csrc, cw, updcB,
                                             atom_list, 0, last ? 0 : 1);

        // conv_mono: gather(type2, src mono -> h2bf); self h2bf; out xcur mono rows
        // (last layer: xcur mono rows never read again -> skip obf write)
        k_gather<<<ngrid, 256, 0, stream>>>(h2bf, h2bf, rowptr, csrc, cw, updcA,
                                            mono_list, cnt, 1, 2);
        k_conv<2><<<ggrid, 256, 0, stream>>>(updcA, Wm, bm_, last ? nullptr : xcur,
                                             aout, nout, last, 0, mono_list, cnt, 1,
                                             nullptr, nullptr, nullptr, nullptr,
                                             nullptr, nullptr, 0, 0);

        ushort* tmp = xprev; xprev = xcur; xcur = tmp;
    }

    // ---- outputs (aout/nout fully written by last-layer epilogues) ----
    k_graph<<<dim3((NG + 3) / 4), 256, 0, stream>>>(ut, n2g, aout, gs, ge, gout);
}

// Round 11
// 979.382 us; speedup vs baseline: 1.1601x; 1.1601x over previous
//
#include <hip/hip_runtime.h>
#include <cstdint>
#include <cstddef>

#define NN 80000
#define NE 500000
#define NG 2000
#define DD 256
#define RR 4
#define LL 3
#define UNITS_TH 150
#define NRSEG (NN*RR)
#define SSEG (3*NRSEG)        // 960000 segments across 3 conv types
#define RD (RR*DD)            // 1024
#define KTOT (RD+DD)          // 1280 (row stride 2560B, non-pow2)
#define MROWS 49280           // compacted-A rows: max(count)+slack

// MFMA GEMM tile (round-5 proven best: 128x128, 256 thr, 66KB LDS, 2 blocks/CU)
#define GBM 128
#define GBN 128
#define GXT ((NN + GBM - 1) / GBM)       // 625 row-tiles
#define GNBLK (16 * ((GXT + 7) / 8))     // pair-swizzled 1-D grid

typedef __attribute__((ext_vector_type(8))) short bf16x8;
typedef __attribute__((ext_vector_type(4))) float f32x4;

__device__ __forceinline__ ushort f2bf(float f) {
    union { float f; uint32_t u; } c; c.f = f;
    uint32_t u = c.u;
    return (ushort)((u + 0x7FFFu + ((u >> 16) & 1u)) >> 16);
}
__device__ __forceinline__ float bf2f(ushort h) {
    union { uint32_t u; float f; } c; c.u = ((uint32_t)h) << 16;
    return c.f;
}

__device__ __forceinline__ void gload16(const void* g, void* l) {
    __builtin_amdgcn_global_load_lds(
        (const __attribute__((address_space(1))) unsigned int*)g,
        (__attribute__((address_space(3))) unsigned int*)l, 16, 0, 0);
}

__device__ inline int edge_type(const int* ut, int s, int d) {
    bool ain = ut[s] >= UNITS_TH, aout = ut[d] >= UNITS_TH;
    return ain ? (aout ? 0 : 1) : (aout ? 3 : 2);  // 3 = unused (m->a)
}

// xbf[n,:] = bf16(emb[ut[n],:])  (or 0)
__global__ void k_init_xbf(const int* __restrict__ ut, const float* __restrict__ emb,
                           ushort* __restrict__ x)
{
    int tid = blockIdx.x * blockDim.x + threadIdx.x;
    int n = tid >> 6, lane = tid & 63;
    if (n >= NN) return;
    int t = ut[n];
    ushort4 u = make_ushort4(0, 0, 0, 0);
    if (t >= 0) {
        float4 v = *reinterpret_cast<const float4*>(emb + (size_t)t * DD + lane * 4);
        u.x = f2bf(v.x); u.y = f2bf(v.y); u.z = f2bf(v.z); u.w = f2bf(v.w);
    }
    *reinterpret_cast<ushort4*>(x + (size_t)n * DD + lane * 4) = u;
}

// wave-aggregated list build: one atomic per wave per class
__global__ void k_lists(const int* __restrict__ ut, int* __restrict__ atom_list,
                        int* __restrict__ mono_list, int* __restrict__ cnt)
{
    int n = blockIdx.x * blockDim.x + threadIdx.x;
    bool valid = n < NN;
    bool atom = valid && (ut[n] >= UNITS_TH);
    bool mono = valid && (ut[n] < UNITS_TH);
    unsigned long long ma = __ballot(atom);
    unsigned long long mb = __ballot(mono);
    int lane = threadIdx.x & 63;
    unsigned long long below = (1ull << lane) - 1ull;
    int ra = __popcll(ma & below);
    int rm = __popcll(mb & below);
    int basea = 0, basem = 0;
    if (lane == 0) {
        if (ma) basea = atomicAdd(cnt + 0, __popcll(ma));
        if (mb) basem = atomicAdd(cnt + 1, __popcll(mb));
    }
    basea = __shfl(basea, 0);
    basem = __shfl(basem, 0);
    if (atom) atom_list[basea + ra] = n;
    if (mono) mono_list[basem + rm] = n;
}

// weights: Wcat[n][0:1024]=W[n][:], [1024:1280]=Ws[n][:], bf16; bias2 = b+bs
__global__ void k_wcat(const float* __restrict__ W, const float* __restrict__ Ws,
                       const float* __restrict__ b, const float* __restrict__ bs,
                       ushort* __restrict__ out, float* __restrict__ bias2)
{
    int n = blockIdx.x;
    const float* wr = W + (size_t)n * RD;
    const float* wsr = Ws + (size_t)n * DD;
    ushort* o = out + (size_t)n * KTOT;
    for (int k = threadIdx.x; k < RD; k += 256) o[k] = f2bf(wr[k]);
    for (int k = threadIdx.x; k < DD; k += 256) o[RD + k] = f2bf(wsr[k]);
    if (threadIdx.x == 0) bias2[n] = b[n] + bs[n];
}

// ---- CSR build (layer-invariant, built once) ----
__global__ void k_csr_count(const int* __restrict__ ut, const int* __restrict__ esrc,
                            const int* __restrict__ edst, const int* __restrict__ erel,
                            int* __restrict__ cnt3)
{
    int e = blockIdx.x * blockDim.x + threadIdx.x;
    if (e >= NE) return;
    int s = esrc[e], d = edst[e];
    int t = edge_type(ut, s, d);
    if (t == 3) return;
    atomicAdd(&cnt3[t * NRSEG + d * RR + erel[e]], 1);
}

__global__ void k_scan_a(const int* __restrict__ in, int* __restrict__ out,
                         int* __restrict__ bsum, int S)
{
    __shared__ int sh[256];
    int base = blockIdx.x * 1024 + threadIdx.x * 4;
    int v[4];
    #pragma unroll
    for (int j = 0; j < 4; j++) v[j] = (base + j < S) ? in[base + j] : 0;
    int tsum = v[0] + v[1] + v[2] + v[3];
    sh[threadIdx.x] = tsum;
    __syncthreads();
    for (int ofs = 1; ofs < 256; ofs <<= 1) {
        int a = sh[threadIdx.x];
        int b = (threadIdx.x >= ofs) ? sh[threadIdx.x - ofs] : 0;
        __syncthreads();
        sh[threadIdx.x] = a + b;
        __syncthreads();
    }
    int excl = sh[threadIdx.x] - tsum;
    if (threadIdx.x == 255) bsum[blockIdx.x] = sh[255];
    int run = excl;
    #pragma unroll
    for (int j = 0; j < 4; j++) {
        if (base + j < S) out[base + j] = run;
        run += v[j];
    }
}

__global__ void k_scan_b(int* __restrict__ bsum, int* __restrict__ total, int NB)
{
    __shared__ int sh[1024];
    int t = threadIdx.x;
    int o = (t < NB) ? bsum[t] : 0;
    sh[t] = o;
    __syncthreads();
    for (int ofs = 1; ofs < 1024; ofs <<= 1) {
        int a = sh[t];
        int b = (t >= ofs) ? sh[t - ofs] : 0;
        __syncthreads();
        sh[t] = a + b;
        __syncthreads();
    }
    if (t < NB) bsum[t] = sh[t] - o;
    if (t == 0) *total = sh[1023];
}

__global__ void k_scan_c(int* __restrict__ rowptr, const int* __restrict__ bofs,
                         const int* __restrict__ total, int S)
{
    int add = bofs[blockIdx.x];
    int base = blockIdx.x * 1024 + threadIdx.x * 4;
    #pragma unroll
    for (int j = 0; j < 4; j++)
        if (base + j < S) rowptr[base + j] += add;
    if (blockIdx.x == 0 && threadIdx.x == 0) rowptr[S] = *total;
}

__global__ void k_csr_fill(const int* __restrict__ ut, const int* __restrict__ esrc,
                           const int* __restrict__ edst, const int* __restrict__ erel,
                           const float* __restrict__ ew, const int* __restrict__ rowptr,
                           int* __restrict__ fill, int* __restrict__ csrc,
                           float* __restrict__ cw)
{
    int e = blockIdx.x * blockDim.x + threadIdx.x;
    if (e >= NE) return;
    int s = esrc[e], d = edst[e];
    int t = edge_type(ut, s, d);
    if (t == 3) return;
    int seg = t * NRSEG + d * RR + erel[e];
    int pos = atomicAdd(&fill[seg], 1);
    int slot = rowptr[seg] + pos;
    csrc[slot] = s;
    cw[slot] = ew[e];
}

// normalize weights in place: cw[e] = (cw[e]>0) ? cw[e]/deg : 0, deg = sum over segment
__global__ void k_norm(const int* __restrict__ rowptr, float* __restrict__ cw)
{
    int s = blockIdx.x * blockDim.x + threadIdx.x;
    if (s >= SSEG) return;
    int a = rowptr[s], b = rowptr[s + 1];
    if (a == b) return;
    float deg = 0.f;
    for (int e = a; e < b; ++e) deg += cw[e];
    float inv = 1.f / ((deg > 0.f) ? deg : 1.f);
    for (int e = a; e < b; ++e) {
        float w = cw[e];
        cw[e] = (w > 0.f) ? w * inv : 0.f;
    }
}

// ---- gather (round-5 proven form: wave-per-node, serial rels, self-copy),
// branch in edge loop removed (pre-normalized cw==0 contributes exactly 0) ----
// updc[i][0:1024] = per-rel weighted sums; updc[i][1024:1280] = xselfp[node]
__global__ void k_gather(const ushort* __restrict__ xsrc, const ushort* __restrict__ xselfp,
                         const int* __restrict__ rowptr,
                         const int* __restrict__ csrc, const float* __restrict__ cw,
                         ushort* __restrict__ updc, const int* __restrict__ list,
                         const int* __restrict__ cnt, int cnt_idx, int t)
{
    int i = blockIdx.x * 4 + (threadIdx.x >> 6);
    if (i >= cnt[cnt_idx]) return;
    int lane = threadIdx.x & 63;
    int node = list[i];
    ushort* orow = updc + (size_t)i * KTOT;
    int segbase = t * NRSEG + node * RR;
    #pragma unroll
    for (int rel = 0; rel < RR; ++rel) {
        int s0 = rowptr[segbase + rel];
        int s1 = rowptr[segbase + rel + 1];
        float a0 = 0.f, a1 = 0.f, a2 = 0.f, a3 = 0.f;
        for (int e = s0; e < s1; ++e) {
            float f = cw[e];
            int src = csrc[e];
            ushort4 v = *reinterpret_cast<const ushort4*>(xsrc + (size_t)src * DD + lane * 4);
            a0 += f * bf2f(v.x); a1 += f * bf2f(v.y);
            a2 += f * bf2f(v.z); a3 += f * bf2f(v.w);
        }
        ushort4 u;
        u.x = f2bf(a0); u.y = f2bf(a1); u.z = f2bf(a2); u.w = f2bf(a3);
        *reinterpret_cast<ushort4*>(orow + rel * DD + lane * 4) = u;
    }
    // self-term copy (bit-identical to reading xselfp in the GEMM)
    ushort4 sv = *reinterpret_cast<const ushort4*>(xselfp + (size_t)node * DD + lane * 4);
    *reinterpret_cast<ushort4*>(orow + RD + lane * 4) = sv;
}

// ---- MFMA conv GEMM (round-5 exact: sequential A incl. self, XCD pair-swizzle) ----
// A = updc [count x 1280] bf16, B = Wcat bf16 [256][1280]. (x,y=0)/(x,y=1) pair
// ids differ by 8 -> same XCD -> duplicate A-tile read is an L2 hit.
template<int CTYPE>
__global__ __launch_bounds__(256) void k_conv(
    const ushort* __restrict__ updc, const ushort* __restrict__ Wc,
    const float* __restrict__ bias2,
    ushort* __restrict__ obf, float* __restrict__ of32,
    float* __restrict__ nf32, int wf32, int nzero,
    const int* __restrict__ list, const int* __restrict__ cnt, int cnt_idx)
{
    int count = cnt[cnt_idx];
    int id = blockIdx.x;
    int g = id >> 4, o = id & 15;
    int y = (o >> 3) & 1;
    int x = (g << 3) | (o & 7);
    int bm = x * GBM;
    if (bm >= count) return;
    int n0 = y * GBN;

    // LDS pool: [0,32K) As dbuf, [32K,64K) Bs dbuf, [64K,64.5K) rowsS.
    // Epilogue aliases [0,64K) as f32 out-tile [128][128].
    __shared__ __align__(16) char smem[66048];
    int* rowsS = (int*)(smem + 65536);

    int tid = threadIdx.x;
    if (tid < GBM) {
        int r = bm + tid;
        rowsS[tid] = (r < count) ? list[r] : 0;   // tail rows masked at write
    }
    __syncthreads();   // rowsS visible; vmcnt drained -> pipeline count clean

    int wid = tid >> 6, lane = tid & 63;
    int srow = lane >> 3;                  // row within 8-row group
    int schunk = (lane & 7) ^ srow;        // swizzled 16B chunk to fetch

    const ushort* baseA[4];
    const ushort* baseW[4];
    #pragma unroll
    for (int it = 0; it < 4; ++it) {
        int m = bm + it * 32 + wid * 8 + srow;               // sequential rows
        baseA[it] = updc + (size_t)m * KTOT + schunk * 8;
        int n = n0 + it * 32 + wid * 8 + srow;
        baseW[it] = Wc + (size_t)n * KTOT + schunk * 8;
    }

    int lr = lane & 15;
    int cbase = (lane >> 4) << 4;   // byte col offset of this lane's 16B frag

    f32x4 acc[4][4] = {};

    auto stage = [&](int t, int buf) {
        int k0 = t * 64;
        char* Ad = smem + buf * 16384 + wid * 1024;
        char* Bd = smem + 32768 + buf * 16384 + wid * 1024;
        #pragma unroll
        for (int it = 0; it < 4; ++it)
            gload16(baseA[it] + k0, Ad + it * 4096);
        #pragma unroll
        for (int it = 0; it < 4; ++it)
            gload16(baseW[it] + k0, Bd + it * 4096);
    };

    auto compute = [&](int buf) {
        const char* Ab = smem + buf * 16384;
        const char* Bb = smem + 32768 + buf * 16384;
        __builtin_amdgcn_s_setprio(1);
        #pragma unroll
        for (int ks = 0; ks < 2; ++ks) {
            int cb = ks * 64 + cbase;
            int cslot = cb >> 4;
            bf16x8 af[4], bfr[4];
            #pragma unroll
            for (int i = 0; i < 4; i++) {
                int row = (wid & 1) * 64 + i * 16 + lr;
                af[i] = *reinterpret_cast<const bf16x8*>(
                    Ab + row * 128 + ((cslot ^ (row & 7)) << 4));
            }
            #pragma unroll
            for (int j = 0; j < 4; j++) {
                int row = (wid >> 1) * 64 + j * 16 + lr;
                bfr[j] = *reinterpret_cast<const bf16x8*>(
                    Bb + row * 128 + ((cslot ^ (row & 7)) << 4));
            }
            #pragma unroll
            for (int i = 0; i < 4; i++)
                #pragma unroll
                for (int j = 0; j < 4; j++)
                    acc[i][j] = __builtin_amdgcn_mfma_f32_16x16x32_bf16(af[i], bfr[j], acc[i][j], 0, 0, 0);
        }
        __builtin_amdgcn_s_setprio(0);
    };

    const int NT = KTOT / 64;   // 20

    stage(0, 0);
    __builtin_amdgcn_sched_barrier(0);
    stage(1, 1);
    __builtin_amdgcn_sched_barrier(0);

    for (int t = 0; t < NT; ++t) {
        int cur = t & 1;
        if (t < NT - 1) asm volatile("s_waitcnt vmcnt(8)" ::: "memory");
        else            asm volatile("s_waitcnt vmcnt(0)" ::: "memory");
        __builtin_amdgcn_s_barrier();
        compute(cur);
        asm volatile("" ::: "memory");
        __builtin_amdgcn_s_barrier();
        if (t + 2 < NT) stage(t + 2, cur);
    }

    // ---- epilogue: bias+relu -> LDS f32 tile -> full-line global stores ----
    float* ftile = (float*)smem;
    int wm = (wid & 1) * 64;
    int wn = (wid >> 1) * 64;
    float bcol[4];
    #pragma unroll
    for (int j = 0; j < 4; j++) bcol[j] = bias2[n0 + wn + j * 16 + lr];
    #pragma unroll
    for (int i = 0; i < 4; i++) {
        int r0 = wm + i * 16 + (lane >> 4) * 4;
        #pragma unroll
        for (int j = 0; j < 4; j++) {
            int c = wn + j * 16 + lr;
            #pragma unroll
            for (int q = 0; q < 4; q++) {
                float v = acc[i][j][q] + bcol[j];
                ftile[(r0 + q) * 128 + c] = fmaxf(v, 0.f);
            }
        }
    }
    __syncthreads();
    int rbase = wid * 32;
    int cc = (lane & 31) * 4;
    #pragma unroll
    for (int p = 0; p < 16; ++p) {
        int row = rbase + p * 2 + (lane >> 5);
        f32x4 v = *reinterpret_cast<const f32x4*>(ftile + row * 128 + cc);
        if (bm + row < count) {
            int node = rowsS[row];
            int c = n0 + cc;
            if (obf) {
                ushort4 ub;
                ub.x = f2bf(v[0]); ub.y = f2bf(v[1]); ub.z = f2bf(v[2]); ub.w = f2bf(v[3]);
                *reinterpret_cast<ushort4*>(obf + (size_t)node * DD + c) = ub;
            }
            if (wf32) {
                float4 fv = make_float4(v[0], v[1], v[2], v[3]);
                *reinterpret_cast<float4*>(of32 + (size_t)node * DD + c) = fv;
                float4 nv = nzero ? make_float4(0.f, 0.f, 0.f, 0.f) : fv;
                *reinterpret_cast<float4*>(nf32 + (size_t)node * DD + c) = nv;
            }
        }
    }
}

__global__ void k_gbounds(const int* __restrict__ n2g, int* __restrict__ gs,
                          int* __restrict__ ge)
{
    int n = blockIdx.x * blockDim.x + threadIdx.x;
    if (n >= NN) return;
    int g = n2g[n];
    atomicMin(&gs[g], n);
    atomicMax(&ge[g], n + 1);
}

__global__ void k_graph(const int* __restrict__ ut, const int* __restrict__ n2g,
                        const float* __restrict__ aout, const int* __restrict__ gs,
                        const int* __restrict__ ge, float* __restrict__ gout)
{
    int g = blockIdx.x * 4 + (threadIdx.x >> 6);
    if (g >= NG) return;
    int lane = threadIdx.x & 63;
    float a0 = 0.f, a1 = 0.f, a2 = 0.f, a3 = 0.f;
    int s = gs[g], e = ge[g];
    if (s < e) {
        for (int n = s; n < e; ++n) {
            if (n2g[n] != g || ut[n] >= UNITS_TH) continue;
            float4 v = *reinterpret_cast<const float4*>(aout + (size_t)n * DD + lane * 4);
            a0 += v.x; a1 += v.y; a2 += v.z; a3 += v.w;
        }
    }
    *reinterpret_cast<float4*>(gout + (size_t)g * DD + lane * 4) =
        make_float4(a0, a1, a2, a3);
}

extern "C" void kernel_launch(void* const* d_in, const int* in_sizes, int n_in,
                              void* d_out, int out_size, void* d_ws, size_t ws_size,
                              hipStream_t stream)
{
    (void)in_sizes; (void)n_in;
    const int* ut    = (const int*)d_in[0];
    const int* esrc  = (const int*)d_in[1];
    const int* edst  = (const int*)d_in[2];
    const int* erel  = (const int*)d_in[3];
    const float* ew  = (const float*)d_in[4];
    const int* n2g   = (const int*)d_in[5];
    const float* emb = (const float*)d_in[6];
    const float* Wp[3]  = {(const float*)d_in[7],  (const float*)d_in[11], (const float*)d_in[15]};
    const float* bp[3]  = {(const float*)d_in[8],  (const float*)d_in[12], (const float*)d_in[16]};
    const float* Wsp[3] = {(const float*)d_in[9],  (const float*)d_in[13], (const float*)d_in[17]};
    const float* bsp[3] = {(const float*)d_in[10], (const float*)d_in[14], (const float*)d_in[18]};

    float* outp = (float*)d_out;
    float* gout = outp;                                  // [G, D]
    float* nout = outp + (size_t)NG * DD;                // [N, D]
    float* aout = nout + (size_t)NN * DD;                // [N, D] final f32 features

    char* wsb = (char*)d_ws;
    size_t off = 0;
    auto alloc = [&](size_t bytes) -> void* {
        void* p = wsb + off;
        off += (bytes + 255) & ~(size_t)255;
        return p;
    };
    ushort* xA     = (ushort*)alloc((size_t)(NN + 1) * DD * 2);    // 41 MB
    ushort* xB     = (ushort*)alloc((size_t)(NN + 1) * DD * 2);    // 41 MB
    ushort* h2bf   = (ushort*)alloc((size_t)(NN + 1) * DD * 2);    // 41 MB
    ushort* updc   = (ushort*)alloc((size_t)MROWS * KTOT * 2);     // 126 MB compacted A
    ushort* Wcat   = (ushort*)alloc((size_t)9 * DD * KTOT * 2);    // 5.9 MB
    float* bias2   = (float*)alloc((size_t)9 * DD * 4);
    int* csrc      = (int*)alloc((size_t)NE * 4);
    float* cw      = (float*)alloc((size_t)NE * 4);
    int* rowptr    = (int*)alloc((size_t)(SSEG + 1) * 4);
    int* cnt3      = (int*)alloc((size_t)SSEG * 4);
    int* bsum      = (int*)alloc(1024 * 4);
    int* total     = (int*)alloc(256);
    int* atom_list = (int*)alloc((size_t)NN * 4);
    int* mono_list = (int*)alloc((size_t)NN * 4);
    int* cnt       = (int*)alloc(256);
    int* gs        = (int*)alloc((size_t)NG * 4);
    int* ge        = (int*)alloc((size_t)NG * 4);

    if (off > ws_size) {
        hipMemsetAsync(d_out, 0x7F, (size_t)out_size * 4, stream);
        return;
    }

    const int NB = (SSEG + 1023) / 1024;

    // ---- one-time precompute ----
    hipMemsetAsync(cnt, 0, 8, stream);
    hipMemsetAsync(cnt3, 0, (size_t)SSEG * 4, stream);
    hipMemsetAsync(gs, 0x7F, (size_t)NG * 4, stream);
    hipMemsetAsync(ge, 0, (size_t)NG * 4, stream);

    k_init_xbf<<<dim3((NN * 64 + 255) / 256), 256, 0, stream>>>(ut, emb, xA);
    k_lists<<<dim3((NN + 255) / 256), 256, 0, stream>>>(ut, atom_list, mono_list, cnt);
    for (int t = 0; t < 3; ++t) {
        for (int l = 0; l < 3; ++l) {
            int tl = t * 3 + l;
            k_wcat<<<dim3(DD), 256, 0, stream>>>(
                Wp[t] + (size_t)l * DD * RD, Wsp[t] + (size_t)l * DD * DD,
                bp[t] + (size_t)l * DD, bsp[t] + (size_t)l * DD,
                Wcat + (size_t)tl * DD * KTOT, bias2 + (size_t)tl * DD);
        }
    }
    k_csr_count<<<dim3((NE + 255) / 256), 256, 0, stream>>>(ut, esrc, edst, erel, cnt3);
    k_scan_a<<<dim3(NB), 256, 0, stream>>>(cnt3, rowptr, bsum, SSEG);
    k_scan_b<<<dim3(1), 1024, 0, stream>>>(bsum, total, NB);
    k_scan_c<<<dim3(NB), 256, 0, stream>>>(rowptr, bsum, total, SSEG);
    hipMemsetAsync(cnt3, 0, (size_t)SSEG * 4, stream);
    k_csr_fill<<<dim3((NE + 255) / 256), 256, 0, stream>>>(ut, esrc, edst, erel, ew,
                                                           rowptr, cnt3, csrc, cw);
    k_norm<<<dim3((SSEG + 255) / 256), 256, 0, stream>>>(rowptr, cw);
    k_gbounds<<<dim3((NN + 255) / 256), 256, 0, stream>>>(n2g, gs, ge);

    dim3 ggrid(GNBLK);
    int ngrid = (NN + 3) / 4;

    ushort* xprev = xA;
    ushort* xcur  = xB;

    for (int l = 0; l < LL; ++l) {
        int last = (l == LL - 1) ? 1 : 0;
        const ushort* Wa = Wcat + (size_t)(0 * 3 + l) * DD * KTOT;
        const ushort* Wc_ = Wcat + (size_t)(1 * 3 + l) * DD * KTOT;
        const ushort* Wm = Wcat + (size_t)(2 * 3 + l) * DD * KTOT;
        const float* ba = bias2 + (size_t)(0 * 3 + l) * DD;
        const float* bc = bias2 + (size_t)(1 * 3 + l) * DD;
        const float* bm_ = bias2 + (size_t)(2 * 3 + l) * DD;

        // conv_atom: gather(type0, src atom -> xprev); self xprev; out xcur atom rows
        k_gather<<<ngrid, 256, 0, stream>>>(xprev, xprev, rowptr, csrc, cw, updc,
                                            atom_list, cnt, 0, 0);
        k_conv<0><<<ggrid, 256, 0, stream>>>(updc, Wa, ba, xcur, aout, nout,
                                             last, 1, atom_list, cnt, 0);

        // conv_cross: gather(type1, src atom -> xcur); self xprev (mono rows); out h2bf
        k_gather<<<ngrid, 256, 0, stream>>>(xcur, xprev, rowptr, csrc, cw, updc,
                                            mono_list, cnt, 1, 1);
        k_conv<1><<<ggrid, 256, 0, stream>>>(updc, Wc_, bc, h2bf, nullptr, nullptr,
                                             0, 0, mono_list, cnt, 1);

        // conv_mono: gather(type2, src mono -> h2bf); self h2bf; out xcur mono rows
        // (last layer: xcur mono rows never read again -> skip obf write)
        k_gather<<<ngrid, 256, 0, stream>>>(h2bf, h2bf, rowptr, csrc, cw, updc,
                                            mono_list, cnt, 1, 2);
        k_conv<2><<<ggrid, 256, 0, stream>>>(updc, Wm, bm_, last ? nullptr : xcur,
                                             aout, nout, last, 0, mono_list, cnt, 1);

        ushort* tmp = xprev; xprev = xcur; xcur = tmp;
    }

    // ---- outputs (aout/nout fully written by last-layer epilogues) ----
    k_graph<<<dim3((NG + 3) / 4), 256, 0, stream>>>(ut, n2g, aout, gs, ge, gout);
}